// Round 20
// baseline (164.537 us; speedup 1.0000x reference)
//
#include <hip/hip_runtime.h>

typedef unsigned short u16;
typedef unsigned int u32;
typedef __attribute__((ext_vector_type(4))) int v4i;
typedef __attribute__((ext_vector_type(4))) float f32x4;
typedef __attribute__((ext_vector_type(16))) float f32x16;
typedef __attribute__((ext_vector_type(4))) u16 v4u;
typedef __attribute__((ext_vector_type(2))) u32 u32x2;
typedef __attribute__((ext_vector_type(8))) __bf16 bf16x8;

#define B_ 4
#define T_ 2048
#define C_ 1024
#define H_ 16
#define HD_ 64
#define C3_ 3072

__device__ __forceinline__ u16 f2b(float f) {
    unsigned u = __builtin_bit_cast(unsigned, f);
    u += 0x7FFFu + ((u >> 16) & 1u);
    return (u16)(u >> 16);
}
__device__ __forceinline__ float b2f(u16 h) {
    unsigned u = ((unsigned)h) << 16;
    return __builtin_bit_cast(float, u);
}
__device__ __forceinline__ u32 pk2(float lo, float hi) {
    __bf16 a = (__bf16)lo, b = (__bf16)hi;
    return (u32)__builtin_bit_cast(u16, a) | ((u32)__builtin_bit_cast(u16, b) << 16);
}
// async global->LDS, 16B per lane; LDS dest = uniform base + lane*16
__device__ __forceinline__ void glds16(const u16* g, u16* l) {
    __builtin_amdgcn_global_load_lds((const __attribute__((address_space(1))) void*)g,
                                     (__attribute__((address_space(3))) void*)l, 16, 0, 0);
}
// 16-lane (DPP-row) sum on the VALU pipe; bit-identical to the xor butterfly.
__device__ __forceinline__ float row16_sum(float v) {
    float x = v, t;
    t = __builtin_bit_cast(float, __builtin_amdgcn_update_dpp(0, __builtin_bit_cast(int, x), 0xB1, 0xF, 0xF, true));  // quad_perm xor1
    x += t;
    t = __builtin_bit_cast(float, __builtin_amdgcn_update_dpp(0, __builtin_bit_cast(int, x), 0x4E, 0xF, 0xF, true));  // quad_perm xor2
    x += t;
    t = __builtin_bit_cast(float, __builtin_amdgcn_update_dpp(0, __builtin_bit_cast(int, x), 0x141, 0xF, 0xF, true)); // row_half_mirror
    x += t;
    t = __builtin_bit_cast(float, __builtin_amdgcn_update_dpp(0, __builtin_bit_cast(int, x), 0x140, 0xF, 0xF, true)); // row_mirror
    x += t;
    return x;
}

// ---------------- prep: all casts + rope table, grid-stride ------------------
__device__ __forceinline__ void cast4(const float* in, u16* out, int i) {
    f32x4 v = *(const f32x4*)(in + (size_t)i * 4);
    v4u o;
    o[0] = f2b(v[0]); o[1] = f2b(v[1]); o[2] = f2b(v[2]); o[3] = f2b(v[3]);
    *(v4u*)(out + (size_t)i * 4) = o;
}
__global__ __launch_bounds__(256) void prep(const float* __restrict__ x, const float* __restrict__ wa,
                                            const float* __restrict__ wp, u16* __restrict__ Xb,
                                            u16* __restrict__ Wab, u16* __restrict__ Wpb,
                                            u16* __restrict__ Rp) {
    for (int i0 = blockIdx.x * 256 + threadIdx.x; i0 < 3211264; i0 += 2048 * 256) {
        int i = i0;
        if (i < 2097152) { cast4(x, Xb, i); continue; }
        i -= 2097152;
        if (i < 786432) { cast4(wa, Wab, i); continue; }
        i -= 786432;
        if (i < 262144) { cast4(wp, Wpb, i); continue; }
        i -= 262144;                               // rope: [0, 65536)
        int t = i >> 5, j = i & 31;
        float invf = exp2f(-(float)j * (13.287712379549449f / 32.0f));  // 10000^(-j/32)
        float fr = (float)t * invf;
        float s, c;
        sincosf(fr, &s, &c);
        Rp[i * 2]     = f2b(c);
        Rp[i * 2 + 1] = f2b(s);
    }
}

// ---------------- GEMM-QKV: 256x128 tile, 8 waves; fused norm/rope/V^T -------
// Waves as 4M x 2N: wave w -> (wm = w>>1) 64-row band, (wn = w&1) 64-col head.
__global__ __launch_bounds__(512) void gemm_qkv(const u16* __restrict__ A, const u16* __restrict__ Bm,
                                                u16* __restrict__ Qn, u16* __restrict__ Kn,
                                                u16* __restrict__ Vt, const u16* __restrict__ rope) {
    const int Kdim = 1024;
    __shared__ u16 As[16384];    // [256][64] swizzled, 32 KB
    __shared__ u16 Bs[8192];     // [128][64] swizzled, 16 KB
    const int tid = threadIdx.x;
    const int F = blockIdx.y * gridDim.x + blockIdx.x;   // grid (24, 32) = 768
    const int cpx = (gridDim.x * gridDim.y) >> 3;
    const int wg = (F & 7) * cpx + (F >> 3);
    const int row0 = (wg / gridDim.x) * 256;
    const int col0 = (wg % gridDim.x) * 128;
    const int w = tid >> 6, lane = tid & 63;
    const int wm = w >> 1, wn = w & 1;
    const int lr = lane & 15, lk = lane >> 4;

    const f32x4 zf = {0.f, 0.f, 0.f, 0.f};
    f32x4 acc[4][4];
#pragma unroll
    for (int m = 0; m < 4; m++)
#pragma unroll
        for (int n = 0; n < 4; n++) acc[m][n] = zf;

    const u16* Ab = A + (size_t)row0 * Kdim;
    const u16* Bb = Bm + (size_t)col0 * Kdim;
    const int srw = lane >> 3;
    const int gch = (lane & 7) ^ (srw & 7);
    const size_t growA[4] = {
        (size_t)(w * 32 + 0 * 8 + srw) * Kdim + gch * 8,
        (size_t)(w * 32 + 1 * 8 + srw) * Kdim + gch * 8,
        (size_t)(w * 32 + 2 * 8 + srw) * Kdim + gch * 8,
        (size_t)(w * 32 + 3 * 8 + srw) * Kdim + gch * 8 };
    const size_t growB[2] = {
        (size_t)(w * 16 + 0 * 8 + srw) * Kdim + gch * 8,
        (size_t)(w * 16 + 1 * 8 + srw) * Kdim + gch * 8 };
    const int rx = lr & 7;

    for (int k0 = 0; k0 < Kdim; k0 += 64) {
#pragma unroll
        for (int j = 0; j < 4; j++) glds16(Ab + growA[j] + k0, As + (w * 32 + j * 8) * 64);
#pragma unroll
        for (int j = 0; j < 2; j++) glds16(Bb + growB[j] + k0, Bs + (w * 16 + j * 8) * 64);
        __syncthreads();
#pragma unroll
        for (int kk = 0; kk < 2; kk++) {
            const int chx = ((kk * 4 + lk) ^ rx) * 8;
            bf16x8 af[4], bfr[4];
#pragma unroll
            for (int m = 0; m < 4; m++) af[m]  = *(const bf16x8*)&As[(wm * 64 + m * 16 + lr) * 64 + chx];
#pragma unroll
            for (int n = 0; n < 4; n++) bfr[n] = *(const bf16x8*)&Bs[(wn * 64 + n * 16 + lr) * 64 + chx];
#pragma unroll
            for (int m = 0; m < 4; m++)
#pragma unroll
                for (int n = 0; n < 4; n++)
                    acc[m][n] = __builtin_amdgcn_mfma_f32_16x16x32_bf16(af[m], bfr[n], acc[m][n], 0, 0, 0);
        }
        __syncthreads();
    }
    // ---- fused epilogue ----
    const u32* rp32 = (const u32*)rope;        // (cos,sin) packed per (t, d<32)
    const int type = col0 >> 10;               // 0=q, 1=k, 2=v (128-col tiles never straddle)
    const int h = ((col0 & 1023) >> 6) + wn;   // head of this wave's 64-col slab
    if (type == 2) {
        // V: transposed store Vt[bh][d][t]; lane packs 4 consecutive t (j=0..3)
#pragma unroll
        for (int m = 0; m < 4; m++)
#pragma unroll
            for (int n = 0; n < 4; n++) {
                const int d = n * 16 + lr;
                const int rr0 = row0 + wm * 64 + m * 16 + lk * 4;
                const int bq = rr0 >> 11, t0 = rr0 & 2047;
                const int bh = bq * 16 + h;
                u32x2 st;
                st[0] = pk2(acc[m][n][0], acc[m][n][1]);
                st[1] = pk2(acc[m][n][2], acc[m][n][3]);
                *(u32x2*)(Vt + ((size_t)bh * HD_ + d) * T_ + t0) = st;
            }
    } else {
        u16* outb = type ? Kn : Qn;
        const float osc = type ? 1.0f : 0.18033688011112042f;   // q: scale*log2(e), folds into rms
#pragma unroll
        for (int m = 0; m < 4; m++) {
            float rmsj[4];
#pragma unroll
            for (int j = 0; j < 4; j++) {
                const float ss = row16_sum(acc[m][0][j] * acc[m][0][j] + acc[m][1][j] * acc[m][1][j]
                                         + acc[m][2][j] * acc[m][2][j] + acc[m][3][j] * acc[m][3][j]);
                rmsj[j] = rsqrtf(ss * (1.f / 64.f) + 1.1920929e-7f) * osc;
            }
#pragma unroll
            for (int n = 0; n < 2; n++)
#pragma unroll
                for (int j = 0; j < 4; j++) {
                    const int d = n * 16 + lr;                 // d < 32
                    const int rr = row0 + wm * 64 + m * 16 + lk * 4 + j;
                    const int bq = rr >> 11, t = rr & 2047;
                    const int bh = bq * 16 + h;
                    const u32 cs = rp32[t * 32 + d];
                    const float c = b2f((u16)(cs & 0xFFFFu));
                    const float s = b2f((u16)(cs >> 16));
                    const float x1 = acc[m][n][j] * rmsj[j];
                    const float x2 = acc[m][n + 2][j] * rmsj[j];
                    u16* bp = outb + ((size_t)bh * T_ + t) * HD_;
                    bp[d]      = f2b(x1 * c + x2 * s);          // y1 = x1*cos + x2*sin
                    bp[d + 32] = f2b(x2 * c - x1 * s);          // y2 = x2*cos - x1*sin
                }
        }
    }
}

// ---------------- GEMM v7 (proj): 256x128 tile, 8 waves, f32 out -------------
// Same K-loop as gemm_qkv; grid (Ndim/128, Mdim/256) = (8, 32) = 256 = 1/CU.
__global__ __launch_bounds__(512) void gemm_bt7(const u16* __restrict__ A, const u16* __restrict__ Bm,
                                                float* __restrict__ Cout, int Mdim, int Ndim, int Kdim) {
    __shared__ u16 As[16384];    // [256][64] swizzled
    __shared__ u16 Bs[8192];     // [128][64] swizzled
    const int tid = threadIdx.x;
    const int F = blockIdx.y * gridDim.x + blockIdx.x;
    const int cpx = (gridDim.x * gridDim.y) >> 3;
    const int wg = (F & 7) * cpx + (F >> 3);
    const int row0 = (wg / gridDim.x) * 256;
    const int col0 = (wg % gridDim.x) * 128;
    const int w = tid >> 6, lane = tid & 63;
    const int wm = w >> 1, wn = w & 1;
    const int lr = lane & 15, lk = lane >> 4;

    const f32x4 zf = {0.f, 0.f, 0.f, 0.f};
    f32x4 acc[4][4];
#pragma unroll
    for (int m = 0; m < 4; m++)
#pragma unroll
        for (int n = 0; n < 4; n++) acc[m][n] = zf;

    const u16* Ab = A + (size_t)row0 * Kdim;
    const u16* Bb = Bm + (size_t)col0 * Kdim;
    const int srw = lane >> 3;
    const int gch = (lane & 7) ^ (srw & 7);
    const size_t growA[4] = {
        (size_t)(w * 32 + 0 * 8 + srw) * Kdim + gch * 8,
        (size_t)(w * 32 + 1 * 8 + srw) * Kdim + gch * 8,
        (size_t)(w * 32 + 2 * 8 + srw) * Kdim + gch * 8,
        (size_t)(w * 32 + 3 * 8 + srw) * Kdim + gch * 8 };
    const size_t growB[2] = {
        (size_t)(w * 16 + 0 * 8 + srw) * Kdim + gch * 8,
        (size_t)(w * 16 + 1 * 8 + srw) * Kdim + gch * 8 };
    const int rx = lr & 7;

    for (int k0 = 0; k0 < Kdim; k0 += 64) {
#pragma unroll
        for (int j = 0; j < 4; j++) glds16(Ab + growA[j] + k0, As + (w * 32 + j * 8) * 64);
#pragma unroll
        for (int j = 0; j < 2; j++) glds16(Bb + growB[j] + k0, Bs + (w * 16 + j * 8) * 64);
        __syncthreads();
#pragma unroll
        for (int kk = 0; kk < 2; kk++) {
            const int chx = ((kk * 4 + lk) ^ rx) * 8;
            bf16x8 af[4], bfr[4];
#pragma unroll
            for (int m = 0; m < 4; m++) af[m]  = *(const bf16x8*)&As[(wm * 64 + m * 16 + lr) * 64 + chx];
#pragma unroll
            for (int n = 0; n < 4; n++) bfr[n] = *(const bf16x8*)&Bs[(wn * 64 + n * 16 + lr) * 64 + chx];
#pragma unroll
            for (int m = 0; m < 4; m++)
#pragma unroll
                for (int n = 0; n < 4; n++)
                    acc[m][n] = __builtin_amdgcn_mfma_f32_16x16x32_bf16(af[m], bfr[n], acc[m][n], 0, 0, 0);
        }
        __syncthreads();
    }
#pragma unroll
    for (int m = 0; m < 4; m++)
#pragma unroll
        for (int n = 0; n < 4; n++) {
            const int rr = row0 + wm * 64 + m * 16 + lk * 4;
            const int cc = col0 + wn * 64 + n * 16 + lr;
#pragma unroll
            for (int j = 0; j < 4; j++)
                Cout[(size_t)(rr + j) * Ndim + cc] = acc[m][n][j];
        }
}

// ---------------- causal flash attention v9: double-buffered 2-phase pipeline
__global__ __launch_bounds__(256, 4) void attn_fwd9(const u16* __restrict__ Qn, const u16* __restrict__ Kn,
                                                    const u16* __restrict__ Vt, u16* __restrict__ Yb) {
    __shared__ u16 Ks[2][4096];
    __shared__ u16 Vs[2][4096];
    const int tid = threadIdx.x;
    const int w = tid >> 6, lane = tid & 63, la = lane & 31, hi = lane >> 5;
    const int gid = blockIdx.x;
    const int bh = gid & 63, qb = 15 - (gid >> 6);
    const int b = bh >> 4, h = bh & 15;
    const int q0w = qb * 128 + w * 32;
    const int q = q0w + la;
    const u16* Qp = Qn + (size_t)bh * T_ * HD_;
    const u16* Kp = Kn + (size_t)bh * T_ * HD_;
    const u16* Vp = Vt + (size_t)bh * HD_ * T_;

    bf16x8 qf[4];
#pragma unroll
    for (int c = 0; c < 4; c++)
        qf[c] = *(const bf16x8*)(Qp + (size_t)q * HD_ + c * 16 + hi * 8);

    v4i oi; oi[0] = oi[1] = oi[2] = oi[3] = 0x3F803F80;        // bf16 1.0 x8
    const bf16x8 onesf = __builtin_bit_cast(bf16x8, oi);

    f32x16 O0, O1, lsum;
#pragma unroll
    for (int r = 0; r < 16; r++) { O0[r] = 0.f; O1[r] = 0.f; lsum[r] = 0.f; }
    const int lastt = q0w >> 6;
    const int ntile = 2 * qb + 2;              // always even
    const int s8 = lane >> 3;
    const int gch = (lane & 7) ^ s8;
    const int Rw = w * 16;
    const size_t kbase = (size_t)(Rw + s8) * HD_ + gch * 8;
    const size_t vbase = (size_t)(Rw + s8) * T_ + gch * 8;
    const int swl = (la & 7) << 3;                               // frag-read XOR

    auto STAGE = [&](int bi, int kv0) {
        glds16(Kp + kbase + (size_t)kv0 * HD_,       &Ks[bi][Rw * 64]);
        glds16(Kp + kbase + (size_t)(kv0 + 8) * HD_, &Ks[bi][Rw * 64 + 512]);
        glds16(Vp + vbase + kv0,                     &Vs[bi][Rw * 64]);
        glds16(Vp + vbase + 8 * T_ + kv0,            &Vs[bi][Rw * 64 + 512]);
    };
    auto COMPUTE = [&](int bi, int kt) {
        const int kv0 = kt * 64;
        f32x16 s0, s1;
#pragma unroll
        for (int r = 0; r < 16; r++) { s0[r] = 0.f; s1[r] = 0.f; }
#pragma unroll
        for (int c = 0; c < 4; c++) {
            const int cb = c * 16 + hi * 8;
            bf16x8 kfa = *(const bf16x8*)&Ks[bi][la * 64 + (cb ^ swl)];
            bf16x8 kfb = *(const bf16x8*)&Ks[bi][(32 + la) * 64 + (cb ^ swl)];
            s0 = __builtin_amdgcn_mfma_f32_32x32x16_bf16(kfa, qf[c], s0, 0, 0, 0);
            s1 = __builtin_amdgcn_mfma_f32_32x32x16_bf16(kfb, qf[c], s1, 0, 0, 0);
        }
        if (kt == lastt) {
#pragma unroll
            for (int r = 0; r < 16; r++) {
                const int cr = (r & 3) + 8 * (r >> 2) + 4 * hi;
                if (kv0 + cr > q)      s0[r] = -3e38f;
                if (kv0 + 32 + cr > q) s1[r] = -3e38f;
            }
        }
        // fixed-m softmax with pre-scaled Q: P = exp2(S); masked -> 0
        float p0[16], p1[16];
#pragma unroll
        for (int r = 0; r < 16; r++) {
            p0[r] = exp2f(s0[r]);
            p1[r] = exp2f(s1[r]);
        }
#pragma unroll
        for (int g = 0; g < 2; g++) {
            u32 P2[8];
#pragma unroll
            for (int j = 0; j < 8; j++)
                P2[j] = g ? pk2(p1[2 * j], p1[2 * j + 1]) : pk2(p0[2 * j], p0[2 * j + 1]);
            auto s02 = __builtin_amdgcn_permlane32_swap((int)P2[0], (int)P2[2], false, false);
            auto s13 = __builtin_amdgcn_permlane32_swap((int)P2[1], (int)P2[3], false, false);
            auto s46 = __builtin_amdgcn_permlane32_swap((int)P2[4], (int)P2[6], false, false);
            auto s57 = __builtin_amdgcn_permlane32_swap((int)P2[5], (int)P2[7], false, false);
            v4i w0, w1;
            w0[0] = s02[0]; w0[1] = s13[0]; w0[2] = s02[1]; w0[3] = s13[1];
            w1[0] = s46[0]; w1[1] = s57[0]; w1[2] = s46[1]; w1[3] = s57[1];
            const bf16x8 pa0 = __builtin_bit_cast(bf16x8, w0);
            const bf16x8 pa1 = __builtin_bit_cast(bf16x8, w1);
            lsum = __builtin_amdgcn_mfma_f32_32x32x16_bf16(onesf, pa0, lsum, 0, 0, 0);
            lsum = __builtin_amdgcn_mfma_f32_32x32x16_bf16(onesf, pa1, lsum, 0, 0, 0);
#pragma unroll
            for (int ks = 0; ks < 2; ks++) {
                const bf16x8 pa = ks ? pa1 : pa0;
                const int cb = g * 32 + ks * 16 + hi * 8;
                bf16x8 vfa = *(const bf16x8*)&Vs[bi][la * 64 + (cb ^ swl)];
                bf16x8 vfb = *(const bf16x8*)&Vs[bi][(32 + la) * 64 + (cb ^ swl)];
                O0 = __builtin_amdgcn_mfma_f32_32x32x16_bf16(vfa, pa, O0, 0, 0, 0);
                O1 = __builtin_amdgcn_mfma_f32_32x32x16_bf16(vfb, pa, O1, 0, 0, 0);
            }
        }
    };

    STAGE(0, 0);
    for (int t = 0; t < ntile; t += 2) {
        __syncthreads();                       // drains vmcnt -> buf0 ready; buf1 readers done
        STAGE(1, (t + 1) * 64);                // prefetch flies under compute
        if (t <= lastt) COMPUTE(0, t);
        __syncthreads();                       // drains vmcnt -> buf1 ready; buf0 readers done
        if (t + 2 < ntile) STAGE(0, (t + 2) * 64);
        if (t + 1 <= lastt) COMPUTE(1, t + 1);
    }

    const float inv = 1.f / lsum[0];
    u16* yrow = Yb + ((size_t)(b * T_) + q) * C_ + h * HD_;
#pragma unroll
    for (int r4 = 0; r4 < 4; r4++) {
        u32x2 st0, st1;
        st0[0] = pk2(O0[r4 * 4 + 0] * inv, O0[r4 * 4 + 1] * inv);
        st0[1] = pk2(O0[r4 * 4 + 2] * inv, O0[r4 * 4 + 3] * inv);
        st1[0] = pk2(O1[r4 * 4 + 0] * inv, O1[r4 * 4 + 1] * inv);
        st1[1] = pk2(O1[r4 * 4 + 2] * inv, O1[r4 * 4 + 3] * inv);
        *(u32x2*)(yrow + r4 * 8 + hi * 4)      = st0;
        *(u32x2*)(yrow + 32 + r4 * 8 + hi * 4) = st1;
    }
}

extern "C" void kernel_launch(void* const* d_in, const int* in_sizes, int n_in,
                              void* d_out, int out_size, void* d_ws, size_t ws_size,
                              hipStream_t stream) {
    const float* x      = (const float*)d_in[0];
    const float* w_attn = (const float*)d_in[1];
    const float* w_proj = (const float*)d_in[2];
    float* out = (float*)d_out;
    char* ws = (char*)d_ws;
    // workspace layout (no QKV buffer), peak ~88.3 MB, no aliasing
    u16* Wpb = (u16*)(ws + 0);              // 2 MB
    u16* Rp  = (u16*)(ws + 2097152);        // 256 KB
    u16* Xb  = (u16*)(ws + 2359296);        // 16 MB
    u16* Wab = (u16*)(ws + 19136512);       // 6 MB
    u16* Qn  = (u16*)(ws + 25427968);       // 16 MB  [bh][t][d], pre-scaled
    u16* Kn  = (u16*)(ws + 42205184);       // 16 MB  [bh][t][d]
    u16* Vt  = (u16*)(ws + 58982400);       // 16 MB  [bh][d][t]
    u16* Yb  = (u16*)(ws + 75759616);       // 16 MB  [b*t][c]

    prep<<<2048, 256, 0, stream>>>(x, w_attn, w_proj, Xb, Wab, Wpb, Rp);
    gemm_qkv<<<dim3(24, 32), 512, 0, stream>>>(Xb, Wab, Qn, Kn, Vt, Rp);
    attn_fwd9<<<1024, 256, 0, stream>>>(Qn, Kn, Vt, Yb);
    gemm_bt7<<<dim3(8, 32), 512, 0, stream>>>(Yb, Wpb, out, 8192, 1024, 1024);
}

// Round 21
// 163.424 us; speedup vs baseline: 1.0068x; 1.0068x over previous
//
#include <hip/hip_runtime.h>

typedef unsigned short u16;
typedef unsigned int u32;
typedef __attribute__((ext_vector_type(4))) int v4i;
typedef __attribute__((ext_vector_type(4))) float f32x4;
typedef __attribute__((ext_vector_type(16))) float f32x16;
typedef __attribute__((ext_vector_type(4))) u16 v4u;
typedef __attribute__((ext_vector_type(2))) u32 u32x2;
typedef __attribute__((ext_vector_type(8))) __bf16 bf16x8;

#define B_ 4
#define T_ 2048
#define C_ 1024
#define H_ 16
#define HD_ 64
#define C3_ 3072

__device__ __forceinline__ u16 f2b(float f) {
    unsigned u = __builtin_bit_cast(unsigned, f);
    u += 0x7FFFu + ((u >> 16) & 1u);
    return (u16)(u >> 16);
}
__device__ __forceinline__ float b2f(u16 h) {
    unsigned u = ((unsigned)h) << 16;
    return __builtin_bit_cast(float, u);
}
__device__ __forceinline__ u32 pk2(float lo, float hi) {
    __bf16 a = (__bf16)lo, b = (__bf16)hi;
    return (u32)__builtin_bit_cast(u16, a) | ((u32)__builtin_bit_cast(u16, b) << 16);
}
// async global->LDS, 16B per lane; LDS dest = uniform base + lane*16
__device__ __forceinline__ void glds16(const u16* g, u16* l) {
    __builtin_amdgcn_global_load_lds((const __attribute__((address_space(1))) void*)g,
                                     (__attribute__((address_space(3))) void*)l, 16, 0, 0);
}
// 16-lane (DPP-row) sum on the VALU pipe; bit-identical to the xor butterfly.
__device__ __forceinline__ float row16_sum(float v) {
    float x = v, t;
    t = __builtin_bit_cast(float, __builtin_amdgcn_update_dpp(0, __builtin_bit_cast(int, x), 0xB1, 0xF, 0xF, true));  // quad_perm xor1
    x += t;
    t = __builtin_bit_cast(float, __builtin_amdgcn_update_dpp(0, __builtin_bit_cast(int, x), 0x4E, 0xF, 0xF, true));  // quad_perm xor2
    x += t;
    t = __builtin_bit_cast(float, __builtin_amdgcn_update_dpp(0, __builtin_bit_cast(int, x), 0x141, 0xF, 0xF, true)); // row_half_mirror
    x += t;
    t = __builtin_bit_cast(float, __builtin_amdgcn_update_dpp(0, __builtin_bit_cast(int, x), 0x140, 0xF, 0xF, true)); // row_mirror
    x += t;
    return x;
}

// ---------------- prep: all casts + rope table, grid-stride ------------------
__device__ __forceinline__ void cast4(const float* in, u16* out, int i) {
    f32x4 v = *(const f32x4*)(in + (size_t)i * 4);
    v4u o;
    o[0] = f2b(v[0]); o[1] = f2b(v[1]); o[2] = f2b(v[2]); o[3] = f2b(v[3]);
    *(v4u*)(out + (size_t)i * 4) = o;
}
__global__ __launch_bounds__(256) void prep(const float* __restrict__ x, const float* __restrict__ wa,
                                            const float* __restrict__ wp, u16* __restrict__ Xb,
                                            u16* __restrict__ Wab, u16* __restrict__ Wpb,
                                            u16* __restrict__ Rp) {
    for (int i0 = blockIdx.x * 256 + threadIdx.x; i0 < 3211264; i0 += 2048 * 256) {
        int i = i0;
        if (i < 2097152) { cast4(x, Xb, i); continue; }
        i -= 2097152;
        if (i < 786432) { cast4(wa, Wab, i); continue; }
        i -= 786432;
        if (i < 262144) { cast4(wp, Wpb, i); continue; }
        i -= 262144;                               // rope: [0, 65536)
        int t = i >> 5, j = i & 31;
        float invf = exp2f(-(float)j * (13.287712379549449f / 32.0f));  // 10000^(-j/32)
        float fr = (float)t * invf;
        float s, c;
        sincosf(fr, &s, &c);
        Rp[i * 2]     = f2b(c);
        Rp[i * 2 + 1] = f2b(s);
    }
}

// ---------------- GEMM v5: 128x128, BK=64 glds + XOR swizzle + XCD remap ----
__device__ __forceinline__ void store_out(u16* p, float v)   { *p = f2b(v); }
__device__ __forceinline__ void store_out(float* p, float v) { *p = v; }

template <typename OutT>
__global__ __launch_bounds__(256) void gemm_bt5(const u16* __restrict__ A, const u16* __restrict__ Bm,
                                                OutT* __restrict__ Cout, int Mdim, int Ndim, int Kdim) {
    __shared__ u16 As[8192];     // [128][64] swizzled, 16 KB
    __shared__ u16 Bs[8192];
    const int tid = threadIdx.x;
    const int F = blockIdx.y * gridDim.x + blockIdx.x;
    const int cpx = (gridDim.x * gridDim.y) >> 3;
    const int wg = (F & 7) * cpx + (F >> 3);
    const int row0 = (wg / gridDim.x) * 128;
    const int col0 = (wg % gridDim.x) * 128;
    const int w = tid >> 6, lane = tid & 63;
    const int wm = w >> 1, wn = w & 1;
    const int lr = lane & 15, lk = lane >> 4;

    const f32x4 zf = {0.f, 0.f, 0.f, 0.f};
    f32x4 acc[4][4];
#pragma unroll
    for (int m = 0; m < 4; m++)
#pragma unroll
        for (int n = 0; n < 4; n++) acc[m][n] = zf;

    const u16* Ab = A + (size_t)row0 * Kdim;
    const u16* Bb = Bm + (size_t)col0 * Kdim;
    const int srw = lane >> 3;
    const int gch = (lane & 7) ^ (srw & 7);
    const size_t grow[4] = {
        (size_t)(w * 32 + 0 * 8 + srw) * Kdim + gch * 8,
        (size_t)(w * 32 + 1 * 8 + srw) * Kdim + gch * 8,
        (size_t)(w * 32 + 2 * 8 + srw) * Kdim + gch * 8,
        (size_t)(w * 32 + 3 * 8 + srw) * Kdim + gch * 8 };
    const int rx = lr & 7;

    for (int k0 = 0; k0 < Kdim; k0 += 64) {
#pragma unroll
        for (int j = 0; j < 4; j++) glds16(Ab + grow[j] + k0, As + (w * 32 + j * 8) * 64);
#pragma unroll
        for (int j = 0; j < 4; j++) glds16(Bb + grow[j] + k0, Bs + (w * 32 + j * 8) * 64);
        __syncthreads();
#pragma unroll
        for (int kk = 0; kk < 2; kk++) {
            const int chx = ((kk * 4 + lk) ^ rx) * 8;
            bf16x8 af[4], bfr[4];
#pragma unroll
            for (int m = 0; m < 4; m++) af[m]  = *(const bf16x8*)&As[(wm * 64 + m * 16 + lr) * 64 + chx];
#pragma unroll
            for (int n = 0; n < 4; n++) bfr[n] = *(const bf16x8*)&Bs[(wn * 64 + n * 16 + lr) * 64 + chx];
#pragma unroll
            for (int m = 0; m < 4; m++)
#pragma unroll
                for (int n = 0; n < 4; n++)
                    acc[m][n] = __builtin_amdgcn_mfma_f32_16x16x32_bf16(af[m], bfr[n], acc[m][n], 0, 0, 0);
        }
        __syncthreads();
    }
#pragma unroll
    for (int m = 0; m < 4; m++)
#pragma unroll
        for (int n = 0; n < 4; n++) {
            const int rr = row0 + wm * 64 + m * 16 + lk * 4;
            const int cc = col0 + wn * 64 + n * 16 + lr;
#pragma unroll
            for (int j = 0; j < 4; j++)
                store_out(Cout + (size_t)(rr + j) * Ndim + cc, acc[m][n][j]);
        }
}

// ---------------- GEMM-QKV: 256x128 tile, 8 waves; fused norm/rope/V^T -------
__global__ __launch_bounds__(512) void gemm_qkv(const u16* __restrict__ A, const u16* __restrict__ Bm,
                                                u16* __restrict__ Qn, u16* __restrict__ Kn,
                                                u16* __restrict__ Vt, const u16* __restrict__ rope) {
    const int Kdim = 1024;
    __shared__ u16 As[16384];    // [256][64] swizzled, 32 KB
    __shared__ u16 Bs[8192];     // [128][64] swizzled, 16 KB
    const int tid = threadIdx.x;
    const int F = blockIdx.y * gridDim.x + blockIdx.x;   // grid (24, 32) = 768
    const int cpx = (gridDim.x * gridDim.y) >> 3;
    const int wg = (F & 7) * cpx + (F >> 3);
    const int row0 = (wg / gridDim.x) * 256;
    const int col0 = (wg % gridDim.x) * 128;
    const int w = tid >> 6, lane = tid & 63;
    const int wm = w >> 1, wn = w & 1;
    const int lr = lane & 15, lk = lane >> 4;

    const f32x4 zf = {0.f, 0.f, 0.f, 0.f};
    f32x4 acc[4][4];
#pragma unroll
    for (int m = 0; m < 4; m++)
#pragma unroll
        for (int n = 0; n < 4; n++) acc[m][n] = zf;

    const u16* Ab = A + (size_t)row0 * Kdim;
    const u16* Bb = Bm + (size_t)col0 * Kdim;
    const int srw = lane >> 3;
    const int gch = (lane & 7) ^ (srw & 7);
    const size_t growA[4] = {
        (size_t)(w * 32 + 0 * 8 + srw) * Kdim + gch * 8,
        (size_t)(w * 32 + 1 * 8 + srw) * Kdim + gch * 8,
        (size_t)(w * 32 + 2 * 8 + srw) * Kdim + gch * 8,
        (size_t)(w * 32 + 3 * 8 + srw) * Kdim + gch * 8 };
    const size_t growB[2] = {
        (size_t)(w * 16 + 0 * 8 + srw) * Kdim + gch * 8,
        (size_t)(w * 16 + 1 * 8 + srw) * Kdim + gch * 8 };
    const int rx = lr & 7;

    for (int k0 = 0; k0 < Kdim; k0 += 64) {
#pragma unroll
        for (int j = 0; j < 4; j++) glds16(Ab + growA[j] + k0, As + (w * 32 + j * 8) * 64);
#pragma unroll
        for (int j = 0; j < 2; j++) glds16(Bb + growB[j] + k0, Bs + (w * 16 + j * 8) * 64);
        __syncthreads();
#pragma unroll
        for (int kk = 0; kk < 2; kk++) {
            const int chx = ((kk * 4 + lk) ^ rx) * 8;
            bf16x8 af[4], bfr[4];
#pragma unroll
            for (int m = 0; m < 4; m++) af[m]  = *(const bf16x8*)&As[(wm * 64 + m * 16 + lr) * 64 + chx];
#pragma unroll
            for (int n = 0; n < 4; n++) bfr[n] = *(const bf16x8*)&Bs[(wn * 64 + n * 16 + lr) * 64 + chx];
#pragma unroll
            for (int m = 0; m < 4; m++)
#pragma unroll
                for (int n = 0; n < 4; n++)
                    acc[m][n] = __builtin_amdgcn_mfma_f32_16x16x32_bf16(af[m], bfr[n], acc[m][n], 0, 0, 0);
        }
        __syncthreads();
    }
    // ---- fused epilogue ----
    const u32* rp32 = (const u32*)rope;        // (cos,sin) packed per (t, d<32)
    const int type = col0 >> 10;               // 0=q, 1=k, 2=v (128-col tiles never straddle)
    const int h = ((col0 & 1023) >> 6) + wn;   // head of this wave's 64-col slab
    if (type == 2) {
        // V: transposed store Vt[bh][d][t]; lane packs 4 consecutive t (j=0..3)
#pragma unroll
        for (int m = 0; m < 4; m++)
#pragma unroll
            for (int n = 0; n < 4; n++) {
                const int d = n * 16 + lr;
                const int rr0 = row0 + wm * 64 + m * 16 + lk * 4;
                const int bq = rr0 >> 11, t0 = rr0 & 2047;
                const int bh = bq * 16 + h;
                u32x2 st;
                st[0] = pk2(acc[m][n][0], acc[m][n][1]);
                st[1] = pk2(acc[m][n][2], acc[m][n][3]);
                *(u32x2*)(Vt + ((size_t)bh * HD_ + d) * T_ + t0) = st;
            }
    } else {
        u16* outb = type ? Kn : Qn;
        const float osc = type ? 1.0f : 0.18033688011112042f;   // q: scale*log2(e), folds into rms
#pragma unroll
        for (int m = 0; m < 4; m++) {
            float rmsj[4];
#pragma unroll
            for (int j = 0; j < 4; j++) {
                const float ss = row16_sum(acc[m][0][j] * acc[m][0][j] + acc[m][1][j] * acc[m][1][j]
                                         + acc[m][2][j] * acc[m][2][j] + acc[m][3][j] * acc[m][3][j]);
                rmsj[j] = rsqrtf(ss * (1.f / 64.f) + 1.1920929e-7f) * osc;
            }
#pragma unroll
            for (int n = 0; n < 2; n++)
#pragma unroll
                for (int j = 0; j < 4; j++) {
                    const int d = n * 16 + lr;                 // d < 32
                    const int rr = row0 + wm * 64 + m * 16 + lk * 4 + j;
                    const int bq = rr >> 11, t = rr & 2047;
                    const int bh = bq * 16 + h;
                    const u32 cs = rp32[t * 32 + d];
                    const float c = b2f((u16)(cs & 0xFFFFu));
                    const float s = b2f((u16)(cs >> 16));
                    const float x1 = acc[m][n][j] * rmsj[j];
                    const float x2 = acc[m][n + 2][j] * rmsj[j];
                    u16* bp = outb + ((size_t)bh * T_ + t) * HD_;
                    bp[d]      = f2b(x1 * c + x2 * s);          // y1 = x1*cos + x2*sin
                    bp[d + 32] = f2b(x2 * c - x1 * s);          // y2 = x2*cos - x1*sin
                }
        }
    }
}

// ---------------- causal flash attention v12: v9 + diagonal upper-half skip --
__global__ __launch_bounds__(256, 4) void attn_fwd12(const u16* __restrict__ Qn, const u16* __restrict__ Kn,
                                                     const u16* __restrict__ Vt, u16* __restrict__ Yb) {
    __shared__ u16 Ks[2][4096];
    __shared__ u16 Vs[2][4096];
    const int tid = threadIdx.x;
    const int w = tid >> 6, lane = tid & 63, la = lane & 31, hi = lane >> 5;
    const int gid = blockIdx.x;
    const int bh = gid & 63, qb = 15 - (gid >> 6);
    const int b = bh >> 4, h = bh & 15;
    const int q0w = qb * 128 + w * 32;
    const int q = q0w + la;
    const u16* Qp = Qn + (size_t)bh * T_ * HD_;
    const u16* Kp = Kn + (size_t)bh * T_ * HD_;
    const u16* Vp = Vt + (size_t)bh * HD_ * T_;

    bf16x8 qf[4];
#pragma unroll
    for (int c = 0; c < 4; c++)
        qf[c] = *(const bf16x8*)(Qp + (size_t)q * HD_ + c * 16 + hi * 8);

    v4i oi; oi[0] = oi[1] = oi[2] = oi[3] = 0x3F803F80;        // bf16 1.0 x8
    const bf16x8 onesf = __builtin_bit_cast(bf16x8, oi);

    f32x16 O0, O1, lsum;
#pragma unroll
    for (int r = 0; r < 16; r++) { O0[r] = 0.f; O1[r] = 0.f; lsum[r] = 0.f; }
    const int lastt = q0w >> 6;
    const int ntile = 2 * qb + 2;              // always even
    // s1-half of the diagonal tile is fully masked when q0w%64==0 (waves 0,2)
    const bool skip1 = (q0w & 32) == 0;
    const int s8 = lane >> 3;
    const int gch = (lane & 7) ^ s8;
    const int Rw = w * 16;
    const size_t kbase = (size_t)(Rw + s8) * HD_ + gch * 8;
    const size_t vbase = (size_t)(Rw + s8) * T_ + gch * 8;
    const int swl = (la & 7) << 3;                               // frag-read XOR

    auto STAGE = [&](int bi, int kv0) {
        glds16(Kp + kbase + (size_t)kv0 * HD_,       &Ks[bi][Rw * 64]);
        glds16(Kp + kbase + (size_t)(kv0 + 8) * HD_, &Ks[bi][Rw * 64 + 512]);
        glds16(Vp + vbase + kv0,                     &Vs[bi][Rw * 64]);
        glds16(Vp + vbase + 8 * T_ + kv0,            &Vs[bi][Rw * 64 + 512]);
    };
    auto COMPUTE = [&](int bi, int kt) {
        const int kv0 = kt * 64;
        const bool half = (kt == lastt) && skip1;    // wave-uniform
        f32x16 s0, s1;
#pragma unroll
        for (int r = 0; r < 16; r++) { s0[r] = 0.f; s1[r] = 0.f; }
#pragma unroll
        for (int c = 0; c < 4; c++) {
            const int cb = c * 16 + hi * 8;
            bf16x8 kfa = *(const bf16x8*)&Ks[bi][la * 64 + (cb ^ swl)];
            s0 = __builtin_amdgcn_mfma_f32_32x32x16_bf16(kfa, qf[c], s0, 0, 0, 0);
            if (!half) {
                bf16x8 kfb = *(const bf16x8*)&Ks[bi][(32 + la) * 64 + (cb ^ swl)];
                s1 = __builtin_amdgcn_mfma_f32_32x32x16_bf16(kfb, qf[c], s1, 0, 0, 0);
            }
        }
        if (kt == lastt) {
#pragma unroll
            for (int r = 0; r < 16; r++) {
                const int cr = (r & 3) + 8 * (r >> 2) + 4 * hi;
                if (kv0 + cr > q)      s0[r] = -3e38f;
                if (kv0 + 32 + cr > q) s1[r] = -3e38f;
            }
        }
        // fixed-m softmax with pre-scaled Q: P = exp2(S); masked -> 0
        float p0[16], p1[16];
#pragma unroll
        for (int r = 0; r < 16; r++) {
            p0[r] = exp2f(s0[r]);
            p1[r] = exp2f(s1[r]);
        }
        const int ng = half ? 1 : 2;
        for (int g = 0; g < ng; g++) {
            u32 P2[8];
#pragma unroll
            for (int j = 0; j < 8; j++)
                P2[j] = g ? pk2(p1[2 * j], p1[2 * j + 1]) : pk2(p0[2 * j], p0[2 * j + 1]);
            auto s02 = __builtin_amdgcn_permlane32_swap((int)P2[0], (int)P2[2], false, false);
            auto s13 = __builtin_amdgcn_permlane32_swap((int)P2[1], (int)P2[3], false, false);
            auto s46 = __builtin_amdgcn_permlane32_swap((int)P2[4], (int)P2[6], false, false);
            auto s57 = __builtin_amdgcn_permlane32_swap((int)P2[5], (int)P2[7], false, false);
            v4i w0, w1;
            w0[0] = s02[0]; w0[1] = s13[0]; w0[2] = s02[1]; w0[3] = s13[1];
            w1[0] = s46[0]; w1[1] = s57[0]; w1[2] = s46[1]; w1[3] = s57[1];
            const bf16x8 pa0 = __builtin_bit_cast(bf16x8, w0);
            const bf16x8 pa1 = __builtin_bit_cast(bf16x8, w1);
            lsum = __builtin_amdgcn_mfma_f32_32x32x16_bf16(onesf, pa0, lsum, 0, 0, 0);
            lsum = __builtin_amdgcn_mfma_f32_32x32x16_bf16(onesf, pa1, lsum, 0, 0, 0);
#pragma unroll
            for (int ks = 0; ks < 2; ks++) {
                const bf16x8 pa = ks ? pa1 : pa0;
                const int cb = g * 32 + ks * 16 + hi * 8;
                bf16x8 vfa = *(const bf16x8*)&Vs[bi][la * 64 + (cb ^ swl)];
                bf16x8 vfb = *(const bf16x8*)&Vs[bi][(32 + la) * 64 + (cb ^ swl)];
                O0 = __builtin_amdgcn_mfma_f32_32x32x16_bf16(vfa, pa, O0, 0, 0, 0);
                O1 = __builtin_amdgcn_mfma_f32_32x32x16_bf16(vfb, pa, O1, 0, 0, 0);
            }
        }
    };

    STAGE(0, 0);
    for (int t = 0; t < ntile; t += 2) {
        __syncthreads();                       // drains vmcnt -> buf0 ready; buf1 readers done
        STAGE(1, (t + 1) * 64);                // prefetch flies under compute
        if (t <= lastt) COMPUTE(0, t);
        __syncthreads();                       // drains vmcnt -> buf1 ready; buf0 readers done
        if (t + 2 < ntile) STAGE(0, (t + 2) * 64);
        if (t + 1 <= lastt) COMPUTE(1, t + 1);
    }

    const float inv = 1.f / lsum[0];
    u16* yrow = Yb + ((size_t)(b * T_) + q) * C_ + h * HD_;
#pragma unroll
    for (int r4 = 0; r4 < 4; r4++) {
        u32x2 st0, st1;
        st0[0] = pk2(O0[r4 * 4 + 0] * inv, O0[r4 * 4 + 1] * inv);
        st0[1] = pk2(O0[r4 * 4 + 2] * inv, O0[r4 * 4 + 3] * inv);
        st1[0] = pk2(O1[r4 * 4 + 0] * inv, O1[r4 * 4 + 1] * inv);
        st1[1] = pk2(O1[r4 * 4 + 2] * inv, O1[r4 * 4 + 3] * inv);
        *(u32x2*)(yrow + r4 * 8 + hi * 4)      = st0;
        *(u32x2*)(yrow + 32 + r4 * 8 + hi * 4) = st1;
    }
}

extern "C" void kernel_launch(void* const* d_in, const int* in_sizes, int n_in,
                              void* d_out, int out_size, void* d_ws, size_t ws_size,
                              hipStream_t stream) {
    const float* x      = (const float*)d_in[0];
    const float* w_attn = (const float*)d_in[1];
    const float* w_proj = (const float*)d_in[2];
    float* out = (float*)d_out;
    char* ws = (char*)d_ws;
    // workspace layout (no QKV buffer), peak ~88.3 MB, no aliasing
    u16* Wpb = (u16*)(ws + 0);              // 2 MB
    u16* Rp  = (u16*)(ws + 2097152);        // 256 KB
    u16* Xb  = (u16*)(ws + 2359296);        // 16 MB
    u16* Wab = (u16*)(ws + 19136512);       // 6 MB
    u16* Qn  = (u16*)(ws + 25427968);       // 16 MB  [bh][t][d], pre-scaled
    u16* Kn  = (u16*)(ws + 42205184);       // 16 MB  [bh][t][d]
    u16* Vt  = (u16*)(ws + 58982400);       // 16 MB  [bh][d][t]
    u16* Yb  = (u16*)(ws + 75759616);       // 16 MB  [b*t][c]

    prep<<<2048, 256, 0, stream>>>(x, w_attn, w_proj, Xb, Wab, Wpb, Rp);
    gemm_qkv<<<dim3(24, 32), 512, 0, stream>>>(Xb, Wab, Qn, Kn, Vt, Rp);
    attn_fwd12<<<1024, 256, 0, stream>>>(Qn, Kn, Vt, Yb);
    gemm_bt5<float><<<dim3(8, 64), 256, 0, stream>>>(Yb, Wpb, out, 8192, 1024, 1024);
}

// Round 22
// 161.494 us; speedup vs baseline: 1.0188x; 1.0119x over previous
//
#include <hip/hip_runtime.h>

typedef unsigned short u16;
typedef unsigned int u32;
typedef __attribute__((ext_vector_type(4))) int v4i;
typedef __attribute__((ext_vector_type(4))) float f32x4;
typedef __attribute__((ext_vector_type(16))) float f32x16;
typedef __attribute__((ext_vector_type(4))) u16 v4u;
typedef __attribute__((ext_vector_type(2))) u32 u32x2;
typedef __attribute__((ext_vector_type(8))) __bf16 bf16x8;

#define B_ 4
#define T_ 2048
#define C_ 1024
#define H_ 16
#define HD_ 64
#define C3_ 3072

__device__ __forceinline__ u16 f2b(float f) {
    unsigned u = __builtin_bit_cast(unsigned, f);
    u += 0x7FFFu + ((u >> 16) & 1u);
    return (u16)(u >> 16);
}
__device__ __forceinline__ float b2f(u16 h) {
    unsigned u = ((unsigned)h) << 16;
    return __builtin_bit_cast(float, u);
}
__device__ __forceinline__ u32 pk2(float lo, float hi) {
    __bf16 a = (__bf16)lo, b = (__bf16)hi;
    return (u32)__builtin_bit_cast(u16, a) | ((u32)__builtin_bit_cast(u16, b) << 16);
}
// async global->LDS, 16B per lane; LDS dest = uniform base + lane*16
__device__ __forceinline__ void glds16(const u16* g, u16* l) {
    __builtin_amdgcn_global_load_lds((const __attribute__((address_space(1))) void*)g,
                                     (__attribute__((address_space(3))) void*)l, 16, 0, 0);
}
// 16-lane (DPP-row) sum on the VALU pipe; bit-identical to the xor butterfly.
__device__ __forceinline__ float row16_sum(float v) {
    float x = v, t;
    t = __builtin_bit_cast(float, __builtin_amdgcn_update_dpp(0, __builtin_bit_cast(int, x), 0xB1, 0xF, 0xF, true));  // quad_perm xor1
    x += t;
    t = __builtin_bit_cast(float, __builtin_amdgcn_update_dpp(0, __builtin_bit_cast(int, x), 0x4E, 0xF, 0xF, true));  // quad_perm xor2
    x += t;
    t = __builtin_bit_cast(float, __builtin_amdgcn_update_dpp(0, __builtin_bit_cast(int, x), 0x141, 0xF, 0xF, true)); // row_half_mirror
    x += t;
    t = __builtin_bit_cast(float, __builtin_amdgcn_update_dpp(0, __builtin_bit_cast(int, x), 0x140, 0xF, 0xF, true)); // row_mirror
    x += t;
    return x;
}

// ---------------- prep: all casts + rope table, grid-stride ------------------
__device__ __forceinline__ void cast4(const float* in, u16* out, int i) {
    f32x4 v = *(const f32x4*)(in + (size_t)i * 4);
    v4u o;
    o[0] = f2b(v[0]); o[1] = f2b(v[1]); o[2] = f2b(v[2]); o[3] = f2b(v[3]);
    *(v4u*)(out + (size_t)i * 4) = o;
}
__global__ __launch_bounds__(256) void prep(const float* __restrict__ x, const float* __restrict__ wa,
                                            const float* __restrict__ wp, u16* __restrict__ Xb,
                                            u16* __restrict__ Wab, u16* __restrict__ Wpb,
                                            u16* __restrict__ Rp) {
    for (int i0 = blockIdx.x * 256 + threadIdx.x; i0 < 3211264; i0 += 2048 * 256) {
        int i = i0;
        if (i < 2097152) { cast4(x, Xb, i); continue; }
        i -= 2097152;
        if (i < 786432) { cast4(wa, Wab, i); continue; }
        i -= 786432;
        if (i < 262144) { cast4(wp, Wpb, i); continue; }
        i -= 262144;                               // rope: [0, 65536)
        int t = i >> 5, j = i & 31;
        float invf = exp2f(-(float)j * (13.287712379549449f / 32.0f));  // 10000^(-j/32)
        float fr = (float)t * invf;
        float s, c;
        sincosf(fr, &s, &c);
        Rp[i * 2]     = f2b(c);
        Rp[i * 2 + 1] = f2b(s);
    }
}

// ---------------- GEMM v5: 128x128, BK=64 glds + XOR swizzle + XCD remap ----
__device__ __forceinline__ void store_out(u16* p, float v)   { *p = f2b(v); }
__device__ __forceinline__ void store_out(float* p, float v) { *p = v; }

template <typename OutT>
__global__ __launch_bounds__(256) void gemm_bt5(const u16* __restrict__ A, const u16* __restrict__ Bm,
                                                OutT* __restrict__ Cout, int Mdim, int Ndim, int Kdim) {
    __shared__ u16 As[8192];     // [128][64] swizzled, 16 KB
    __shared__ u16 Bs[8192];
    const int tid = threadIdx.x;
    const int F = blockIdx.y * gridDim.x + blockIdx.x;
    const int cpx = (gridDim.x * gridDim.y) >> 3;
    const int wg = (F & 7) * cpx + (F >> 3);
    const int row0 = (wg / gridDim.x) * 128;
    const int col0 = (wg % gridDim.x) * 128;
    const int w = tid >> 6, lane = tid & 63;
    const int wm = w >> 1, wn = w & 1;
    const int lr = lane & 15, lk = lane >> 4;

    const f32x4 zf = {0.f, 0.f, 0.f, 0.f};
    f32x4 acc[4][4];
#pragma unroll
    for (int m = 0; m < 4; m++)
#pragma unroll
        for (int n = 0; n < 4; n++) acc[m][n] = zf;

    const u16* Ab = A + (size_t)row0 * Kdim;
    const u16* Bb = Bm + (size_t)col0 * Kdim;
    const int srw = lane >> 3;
    const int gch = (lane & 7) ^ (srw & 7);
    const size_t grow[4] = {
        (size_t)(w * 32 + 0 * 8 + srw) * Kdim + gch * 8,
        (size_t)(w * 32 + 1 * 8 + srw) * Kdim + gch * 8,
        (size_t)(w * 32 + 2 * 8 + srw) * Kdim + gch * 8,
        (size_t)(w * 32 + 3 * 8 + srw) * Kdim + gch * 8 };
    const int rx = lr & 7;

    for (int k0 = 0; k0 < Kdim; k0 += 64) {
#pragma unroll
        for (int j = 0; j < 4; j++) glds16(Ab + grow[j] + k0, As + (w * 32 + j * 8) * 64);
#pragma unroll
        for (int j = 0; j < 4; j++) glds16(Bb + grow[j] + k0, Bs + (w * 32 + j * 8) * 64);
        __syncthreads();
#pragma unroll
        for (int kk = 0; kk < 2; kk++) {
            const int chx = ((kk * 4 + lk) ^ rx) * 8;
            bf16x8 af[4], bfr[4];
#pragma unroll
            for (int m = 0; m < 4; m++) af[m]  = *(const bf16x8*)&As[(wm * 64 + m * 16 + lr) * 64 + chx];
#pragma unroll
            for (int n = 0; n < 4; n++) bfr[n] = *(const bf16x8*)&Bs[(wn * 64 + n * 16 + lr) * 64 + chx];
#pragma unroll
            for (int m = 0; m < 4; m++)
#pragma unroll
                for (int n = 0; n < 4; n++)
                    acc[m][n] = __builtin_amdgcn_mfma_f32_16x16x32_bf16(af[m], bfr[n], acc[m][n], 0, 0, 0);
        }
        __syncthreads();
    }
#pragma unroll
    for (int m = 0; m < 4; m++)
#pragma unroll
        for (int n = 0; n < 4; n++) {
            const int rr = row0 + wm * 64 + m * 16 + lk * 4;
            const int cc = col0 + wn * 64 + n * 16 + lr;
#pragma unroll
            for (int j = 0; j < 4; j++)
                store_out(Cout + (size_t)(rr + j) * Ndim + cc, acc[m][n][j]);
        }
}

// ---------------- GEMM-QKV: 256x128 tile, 8 waves; fused norm/rope/V^T -------
__global__ __launch_bounds__(512) void gemm_qkv(const u16* __restrict__ A, const u16* __restrict__ Bm,
                                                u16* __restrict__ Qn, u16* __restrict__ Kn,
                                                u16* __restrict__ Vt, const u16* __restrict__ rope) {
    const int Kdim = 1024;
    __shared__ u16 As[16384];    // [256][64] swizzled, 32 KB
    __shared__ u16 Bs[8192];     // [128][64] swizzled, 16 KB
    const int tid = threadIdx.x;
    const int F = blockIdx.y * gridDim.x + blockIdx.x;   // grid (24, 32) = 768
    const int cpx = (gridDim.x * gridDim.y) >> 3;
    const int wg = (F & 7) * cpx + (F >> 3);
    const int row0 = (wg / gridDim.x) * 256;
    const int col0 = (wg % gridDim.x) * 128;
    const int w = tid >> 6, lane = tid & 63;
    const int wm = w >> 1, wn = w & 1;
    const int lr = lane & 15, lk = lane >> 4;

    const f32x4 zf = {0.f, 0.f, 0.f, 0.f};
    f32x4 acc[4][4];
#pragma unroll
    for (int m = 0; m < 4; m++)
#pragma unroll
        for (int n = 0; n < 4; n++) acc[m][n] = zf;

    const u16* Ab = A + (size_t)row0 * Kdim;
    const u16* Bb = Bm + (size_t)col0 * Kdim;
    const int srw = lane >> 3;
    const int gch = (lane & 7) ^ (srw & 7);
    const size_t growA[4] = {
        (size_t)(w * 32 + 0 * 8 + srw) * Kdim + gch * 8,
        (size_t)(w * 32 + 1 * 8 + srw) * Kdim + gch * 8,
        (size_t)(w * 32 + 2 * 8 + srw) * Kdim + gch * 8,
        (size_t)(w * 32 + 3 * 8 + srw) * Kdim + gch * 8 };
    const size_t growB[2] = {
        (size_t)(w * 16 + 0 * 8 + srw) * Kdim + gch * 8,
        (size_t)(w * 16 + 1 * 8 + srw) * Kdim + gch * 8 };
    const int rx = lr & 7;

    for (int k0 = 0; k0 < Kdim; k0 += 64) {
#pragma unroll
        for (int j = 0; j < 4; j++) glds16(Ab + growA[j] + k0, As + (w * 32 + j * 8) * 64);
#pragma unroll
        for (int j = 0; j < 2; j++) glds16(Bb + growB[j] + k0, Bs + (w * 16 + j * 8) * 64);
        __syncthreads();
#pragma unroll
        for (int kk = 0; kk < 2; kk++) {
            const int chx = ((kk * 4 + lk) ^ rx) * 8;
            bf16x8 af[4], bfr[4];
#pragma unroll
            for (int m = 0; m < 4; m++) af[m]  = *(const bf16x8*)&As[(wm * 64 + m * 16 + lr) * 64 + chx];
#pragma unroll
            for (int n = 0; n < 4; n++) bfr[n] = *(const bf16x8*)&Bs[(wn * 64 + n * 16 + lr) * 64 + chx];
#pragma unroll
            for (int m = 0; m < 4; m++)
#pragma unroll
                for (int n = 0; n < 4; n++)
                    acc[m][n] = __builtin_amdgcn_mfma_f32_16x16x32_bf16(af[m], bfr[n], acc[m][n], 0, 0, 0);
        }
        __syncthreads();
    }
    // ---- fused epilogue ----
    const u32* rp32 = (const u32*)rope;        // (cos,sin) packed per (t, d<32)
    const int type = col0 >> 10;               // 0=q, 1=k, 2=v (128-col tiles never straddle)
    const int h = ((col0 & 1023) >> 6) + wn;   // head of this wave's 64-col slab
    if (type == 2) {
        // V: transposed store Vt[bh][d][t]; lane packs 4 consecutive t (j=0..3)
#pragma unroll
        for (int m = 0; m < 4; m++)
#pragma unroll
            for (int n = 0; n < 4; n++) {
                const int d = n * 16 + lr;
                const int rr0 = row0 + wm * 64 + m * 16 + lk * 4;
                const int bq = rr0 >> 11, t0 = rr0 & 2047;
                const int bh = bq * 16 + h;
                u32x2 st;
                st[0] = pk2(acc[m][n][0], acc[m][n][1]);
                st[1] = pk2(acc[m][n][2], acc[m][n][3]);
                *(u32x2*)(Vt + ((size_t)bh * HD_ + d) * T_ + t0) = st;
            }
    } else {
        u16* outb = type ? Kn : Qn;
        const float osc = type ? 1.0f : 0.18033688011112042f;   // q: scale*log2(e), folds into rms
#pragma unroll
        for (int m = 0; m < 4; m++) {
            float rmsj[4];
#pragma unroll
            for (int j = 0; j < 4; j++) {
                const float ss = row16_sum(acc[m][0][j] * acc[m][0][j] + acc[m][1][j] * acc[m][1][j]
                                         + acc[m][2][j] * acc[m][2][j] + acc[m][3][j] * acc[m][3][j]);
                rmsj[j] = rsqrtf(ss * (1.f / 64.f) + 1.1920929e-7f) * osc;
            }
#pragma unroll
            for (int n = 0; n < 2; n++)
#pragma unroll
                for (int j = 0; j < 4; j++) {
                    const int d = n * 16 + lr;                 // d < 32
                    const int rr = row0 + wm * 64 + m * 16 + lk * 4 + j;
                    const int bq = rr >> 11, t = rr & 2047;
                    const int bh = bq * 16 + h;
                    const u32 cs = rp32[t * 32 + d];
                    const float c = b2f((u16)(cs & 0xFFFFu));
                    const float s = b2f((u16)(cs >> 16));
                    const float x1 = acc[m][n][j] * rmsj[j];
                    const float x2 = acc[m][n + 2][j] * rmsj[j];
                    u16* bp = outb + ((size_t)bh * T_ + t) * HD_;
                    bp[d]      = f2b(x1 * c + x2 * s);          // y1 = x1*cos + x2*sin
                    bp[d + 32] = f2b(x2 * c - x1 * s);          // y2 = x2*cos - x1*sin
                }
        }
    }
}

// ---------------- causal flash attention v13: v9 + HOISTED diagonal-half skip
__global__ __launch_bounds__(256, 4) void attn_fwd13(const u16* __restrict__ Qn, const u16* __restrict__ Kn,
                                                     const u16* __restrict__ Vt, u16* __restrict__ Yb) {
    __shared__ u16 Ks[2][4096];
    __shared__ u16 Vs[2][4096];
    const int tid = threadIdx.x;
    const int w = tid >> 6, lane = tid & 63, la = lane & 31, hi = lane >> 5;
    const int gid = blockIdx.x;
    const int bh = gid & 63, qb = 15 - (gid >> 6);
    const int b = bh >> 4, h = bh & 15;
    const int q0w = qb * 128 + w * 32;
    const int q = q0w + la;
    const u16* Qp = Qn + (size_t)bh * T_ * HD_;
    const u16* Kp = Kn + (size_t)bh * T_ * HD_;
    const u16* Vp = Vt + (size_t)bh * HD_ * T_;

    bf16x8 qf[4];
#pragma unroll
    for (int c = 0; c < 4; c++)
        qf[c] = *(const bf16x8*)(Qp + (size_t)q * HD_ + c * 16 + hi * 8);

    v4i oi; oi[0] = oi[1] = oi[2] = oi[3] = 0x3F803F80;        // bf16 1.0 x8
    const bf16x8 onesf = __builtin_bit_cast(bf16x8, oi);

    f32x16 O0, O1, lsum;
#pragma unroll
    for (int r = 0; r < 16; r++) { O0[r] = 0.f; O1[r] = 0.f; lsum[r] = 0.f; }
    const int lastt = q0w >> 6;
    const int ntile = 2 * qb + 2;              // always even
    const bool skip1 = (q0w & 32) == 0;        // diag upper 32 keys fully masked (waves 0,2)
    const int s8 = lane >> 3;
    const int gch = (lane & 7) ^ s8;
    const int Rw = w * 16;
    const size_t kbase = (size_t)(Rw + s8) * HD_ + gch * 8;
    const size_t vbase = (size_t)(Rw + s8) * T_ + gch * 8;
    const int swl = (la & 7) << 3;                               // frag-read XOR

    auto STAGE = [&](int bi, int kv0) {
        glds16(Kp + kbase + (size_t)kv0 * HD_,       &Ks[bi][Rw * 64]);
        glds16(Kp + kbase + (size_t)(kv0 + 8) * HD_, &Ks[bi][Rw * 64 + 512]);
        glds16(Vp + vbase + kv0,                     &Vs[bi][Rw * 64]);
        glds16(Vp + vbase + 8 * T_ + kv0,            &Vs[bi][Rw * 64 + 512]);
    };
    // FULL tile body — byte-identical to R19's COMPUTE (branch-free)
    auto COMPUTE_FULL = [&](int bi, int kt) {
        const int kv0 = kt * 64;
        f32x16 s0, s1;
#pragma unroll
        for (int r = 0; r < 16; r++) { s0[r] = 0.f; s1[r] = 0.f; }
#pragma unroll
        for (int c = 0; c < 4; c++) {
            const int cb = c * 16 + hi * 8;
            bf16x8 kfa = *(const bf16x8*)&Ks[bi][la * 64 + (cb ^ swl)];
            bf16x8 kfb = *(const bf16x8*)&Ks[bi][(32 + la) * 64 + (cb ^ swl)];
            s0 = __builtin_amdgcn_mfma_f32_32x32x16_bf16(kfa, qf[c], s0, 0, 0, 0);
            s1 = __builtin_amdgcn_mfma_f32_32x32x16_bf16(kfb, qf[c], s1, 0, 0, 0);
        }
        if (kt == lastt) {
#pragma unroll
            for (int r = 0; r < 16; r++) {
                const int cr = (r & 3) + 8 * (r >> 2) + 4 * hi;
                if (kv0 + cr > q)      s0[r] = -3e38f;
                if (kv0 + 32 + cr > q) s1[r] = -3e38f;
            }
        }
        float p0[16], p1[16];
#pragma unroll
        for (int r = 0; r < 16; r++) {
            p0[r] = exp2f(s0[r]);
            p1[r] = exp2f(s1[r]);
        }
#pragma unroll
        for (int g = 0; g < 2; g++) {
            u32 P2[8];
#pragma unroll
            for (int j = 0; j < 8; j++)
                P2[j] = g ? pk2(p1[2 * j], p1[2 * j + 1]) : pk2(p0[2 * j], p0[2 * j + 1]);
            auto s02 = __builtin_amdgcn_permlane32_swap((int)P2[0], (int)P2[2], false, false);
            auto s13 = __builtin_amdgcn_permlane32_swap((int)P2[1], (int)P2[3], false, false);
            auto s46 = __builtin_amdgcn_permlane32_swap((int)P2[4], (int)P2[6], false, false);
            auto s57 = __builtin_amdgcn_permlane32_swap((int)P2[5], (int)P2[7], false, false);
            v4i w0, w1;
            w0[0] = s02[0]; w0[1] = s13[0]; w0[2] = s02[1]; w0[3] = s13[1];
            w1[0] = s46[0]; w1[1] = s57[0]; w1[2] = s46[1]; w1[3] = s57[1];
            const bf16x8 pa0 = __builtin_bit_cast(bf16x8, w0);
            const bf16x8 pa1 = __builtin_bit_cast(bf16x8, w1);
            lsum = __builtin_amdgcn_mfma_f32_32x32x16_bf16(onesf, pa0, lsum, 0, 0, 0);
            lsum = __builtin_amdgcn_mfma_f32_32x32x16_bf16(onesf, pa1, lsum, 0, 0, 0);
#pragma unroll
            for (int ks = 0; ks < 2; ks++) {
                const bf16x8 pa = ks ? pa1 : pa0;
                const int cb = g * 32 + ks * 16 + hi * 8;
                bf16x8 vfa = *(const bf16x8*)&Vs[bi][la * 64 + (cb ^ swl)];
                bf16x8 vfb = *(const bf16x8*)&Vs[bi][(32 + la) * 64 + (cb ^ swl)];
                O0 = __builtin_amdgcn_mfma_f32_32x32x16_bf16(vfa, pa, O0, 0, 0, 0);
                O1 = __builtin_amdgcn_mfma_f32_32x32x16_bf16(vfb, pa, O1, 0, 0, 0);
            }
        }
    };
    // HALF tile body — only first 32 keys live (diag tile of waves 0,2); branch-free
    auto COMPUTE_HALF = [&](int bi, int kv0) {
        f32x16 s0;
#pragma unroll
        for (int r = 0; r < 16; r++) s0[r] = 0.f;
#pragma unroll
        for (int c = 0; c < 4; c++) {
            const int cb = c * 16 + hi * 8;
            bf16x8 kfa = *(const bf16x8*)&Ks[bi][la * 64 + (cb ^ swl)];
            s0 = __builtin_amdgcn_mfma_f32_32x32x16_bf16(kfa, qf[c], s0, 0, 0, 0);
        }
#pragma unroll
        for (int r = 0; r < 16; r++) {
            const int cr = (r & 3) + 8 * (r >> 2) + 4 * hi;
            if (kv0 + cr > q) s0[r] = -3e38f;
        }
        float p0[16];
#pragma unroll
        for (int r = 0; r < 16; r++) p0[r] = exp2f(s0[r]);
        u32 P2[8];
#pragma unroll
        for (int j = 0; j < 8; j++) P2[j] = pk2(p0[2 * j], p0[2 * j + 1]);
        auto s02 = __builtin_amdgcn_permlane32_swap((int)P2[0], (int)P2[2], false, false);
        auto s13 = __builtin_amdgcn_permlane32_swap((int)P2[1], (int)P2[3], false, false);
        auto s46 = __builtin_amdgcn_permlane32_swap((int)P2[4], (int)P2[6], false, false);
        auto s57 = __builtin_amdgcn_permlane32_swap((int)P2[5], (int)P2[7], false, false);
        v4i w0, w1;
        w0[0] = s02[0]; w0[1] = s13[0]; w0[2] = s02[1]; w0[3] = s13[1];
        w1[0] = s46[0]; w1[1] = s57[0]; w1[2] = s46[1]; w1[3] = s57[1];
        const bf16x8 pa0 = __builtin_bit_cast(bf16x8, w0);
        const bf16x8 pa1 = __builtin_bit_cast(bf16x8, w1);
        lsum = __builtin_amdgcn_mfma_f32_32x32x16_bf16(onesf, pa0, lsum, 0, 0, 0);
        lsum = __builtin_amdgcn_mfma_f32_32x32x16_bf16(onesf, pa1, lsum, 0, 0, 0);
#pragma unroll
        for (int ks = 0; ks < 2; ks++) {
            const bf16x8 pa = ks ? pa1 : pa0;
            const int cb = ks * 16 + hi * 8;
            bf16x8 vfa = *(const bf16x8*)&Vs[bi][la * 64 + (cb ^ swl)];
            bf16x8 vfb = *(const bf16x8*)&Vs[bi][(32 + la) * 64 + (cb ^ swl)];
            O0 = __builtin_amdgcn_mfma_f32_32x32x16_bf16(vfa, pa, O0, 0, 0, 0);
            O1 = __builtin_amdgcn_mfma_f32_32x32x16_bf16(vfb, pa, O1, 0, 0, 0);
        }
    };
    auto COMPUTE = [&](int bi, int kt) {
        if (kt == lastt && skip1) COMPUTE_HALF(bi, kt * 64);
        else                      COMPUTE_FULL(bi, kt);
    };

    STAGE(0, 0);
    for (int t = 0; t < ntile; t += 2) {
        __syncthreads();                       // drains vmcnt -> buf0 ready; buf1 readers done
        STAGE(1, (t + 1) * 64);                // prefetch flies under compute
        if (t <= lastt) COMPUTE(0, t);
        __syncthreads();                       // drains vmcnt -> buf1 ready; buf0 readers done
        if (t + 2 < ntile) STAGE(0, (t + 2) * 64);
        if (t + 1 <= lastt) COMPUTE(1, t + 1);
    }

    const float inv = 1.f / lsum[0];
    u16* yrow = Yb + ((size_t)(b * T_) + q) * C_ + h * HD_;
#pragma unroll
    for (int r4 = 0; r4 < 4; r4++) {
        u32x2 st0, st1;
        st0[0] = pk2(O0[r4 * 4 + 0] * inv, O0[r4 * 4 + 1] * inv);
        st0[1] = pk2(O0[r4 * 4 + 2] * inv, O0[r4 * 4 + 3] * inv);
        st1[0] = pk2(O1[r4 * 4 + 0] * inv, O1[r4 * 4 + 1] * inv);
        st1[1] = pk2(O1[r4 * 4 + 2] * inv, O1[r4 * 4 + 3] * inv);
        *(u32x2*)(yrow + r4 * 8 + hi * 4)      = st0;
        *(u32x2*)(yrow + 32 + r4 * 8 + hi * 4) = st1;
    }
}

extern "C" void kernel_launch(void* const* d_in, const int* in_sizes, int n_in,
                              void* d_out, int out_size, void* d_ws, size_t ws_size,
                              hipStream_t stream) {
    const float* x      = (const float*)d_in[0];
    const float* w_attn = (const float*)d_in[1];
    const float* w_proj = (const float*)d_in[2];
    float* out = (float*)d_out;
    char* ws = (char*)d_ws;
    // workspace layout (no QKV buffer), peak ~88.3 MB, no aliasing
    u16* Wpb = (u16*)(ws + 0);              // 2 MB
    u16* Rp  = (u16*)(ws + 2097152);        // 256 KB
    u16* Xb  = (u16*)(ws + 2359296);        // 16 MB
    u16* Wab = (u16*)(ws + 19136512);       // 6 MB
    u16* Qn  = (u16*)(ws + 25427968);       // 16 MB  [bh][t][d], pre-scaled
    u16* Kn  = (u16*)(ws + 42205184);       // 16 MB  [bh][t][d]
    u16* Vt  = (u16*)(ws + 58982400);       // 16 MB  [bh][d][t]
    u16* Yb  = (u16*)(ws + 75759616);       // 16 MB  [b*t][c]

    prep<<<2048, 256, 0, stream>>>(x, w_attn, w_proj, Xb, Wab, Wpb, Rp);
    gemm_qkv<<<dim3(24, 32), 512, 0, stream>>>(Xb, Wab, Qn, Kn, Vt, Rp);
    attn_fwd13<<<1024, 256, 0, stream>>>(Qn, Kn, Vt, Yb);
    gemm_bt5<float><<<dim3(8, 64), 256, 0, stream>>>(Yb, Wpb, out, 8192, 1024, 1024);
}